// Round 2
// baseline (324.212 us; speedup 1.0000x reference)
//
#include <hip/hip_runtime.h>
#include <stdint.h>

#define B_ 2
#define T_ 2048
#define C_ 2048
#define H_ 16
#define D_ 128
#define W_ 512
#define M_ (B_*T_)      // 4096
#define N1_ (3*C_)      // 6144

typedef short bf16x8 __attribute__((ext_vector_type(8)));
typedef unsigned short u16x8 __attribute__((ext_vector_type(8)));
typedef float f32x4 __attribute__((ext_vector_type(4)));

__device__ __forceinline__ unsigned short f2bf(float f) {
  union { float f; unsigned u; } v; v.f = f;
  unsigned r = v.u + 0x7fffu + ((v.u >> 16) & 1u);
  return (unsigned short)(r >> 16);
}
__device__ __forceinline__ float bf2f(unsigned short b) {
  union { unsigned u; float f; } v; v.u = ((unsigned)b) << 16;
  return v.f;
}

__device__ __forceinline__ void gload_lds16(const void* g, void* l) {
  __builtin_amdgcn_global_load_lds((const __attribute__((address_space(1))) void*)g,
                                   (__attribute__((address_space(3))) void*)l, 16, 0, 0);
}

// ---------- fp32 -> bf16 convert ----------
__global__ void k_cvt(const float* __restrict__ s, unsigned short* __restrict__ d, int n) {
  int i = (blockIdx.x * blockDim.x + threadIdx.x) * 8;
  if (i >= n) return;
  float4 a = *(const float4*)(s + i);
  float4 b = *(const float4*)(s + i + 4);
  u16x8 o;
  o[0]=f2bf(a.x); o[1]=f2bf(a.y); o[2]=f2bf(a.z); o[3]=f2bf(a.w);
  o[4]=f2bf(b.x); o[5]=f2bf(b.y); o[6]=f2bf(b.z); o[7]=f2bf(b.w);
  *(u16x8*)(d + i) = o;
}

// ---------- transpose + convert: src [R][Cc] f32 -> dst [Cc][R] bf16 ----------
__global__ void k_tcvt(const float* __restrict__ s, unsigned short* __restrict__ d, int R, int Cc) {
  __shared__ float tile[32][33];
  int c0 = blockIdx.x * 32, r0 = blockIdx.y * 32;
  int tx = threadIdx.x & 31, ty = threadIdx.x >> 5;
  #pragma unroll
  for (int j = 0; j < 32; j += 8) tile[ty + j][tx] = s[(size_t)(r0 + ty + j) * Cc + c0 + tx];
  __syncthreads();
  #pragma unroll
  for (int j = 0; j < 32; j += 8) d[(size_t)(c0 + ty + j) * R + r0 + tx] = f2bf(tile[tx][ty + j]);
}

// ---------- 256x256 8-phase GEMM: C[M][N] = A[M][K] * Bt[N][K]^T ----------
// LDS per matrix: [parity][khalf][256 rows][32 k] bf16, st_16x32 XOR swizzle.

__device__ __forceinline__ void stage_half(const unsigned short* __restrict__ gbase,
                                           int row0, int K, int kt, int kh,
                                           unsigned short* lds_region, int tid) {
  const unsigned short* gsrc = gbase + (size_t)row0 * K + kt * 64 + kh * 32;
  #pragma unroll
  for (int is = 0; is < 2; ++is) {
    int o = (is * 512 + tid) * 16;            // linear dest byte offset in 16KB region
    int s = o ^ (((o >> 9) & 1) << 5);        // pre-swizzled source (involution)
    int row = s >> 6;
    int cb  = s & 63;
    gload_lds16((const char*)(gsrc + (size_t)row * K) + cb, (char*)lds_region + o);
  }
}

__device__ __forceinline__ bf16x8 frag_ld(const unsigned short* region, int row, int lg) {
  int nat = row * 64 + lg * 16;
  int s = nat ^ (((nat >> 9) & 1) << 5);      // swizzled read
  return *(const bf16x8*)((const char*)region + s);
}

template<bool F32OUT>
__global__ __launch_bounds__(512, 2) void k_gemm8(const unsigned short* __restrict__ A,
                                                  const unsigned short* __restrict__ Bt,
                                                  void* __restrict__ Cp,
                                                  int Ntot, int K) {
  __shared__ unsigned short As[2][2][256 * 32];
  __shared__ unsigned short Bs[2][2][256 * 32];
  const int tid = threadIdx.x, lane = tid & 63, wv = tid >> 6;
  const int wm = wv >> 2, wn = wv & 3;
  const int lr = lane & 15, lg = lane >> 4;

  // bijective XCD-aware block swizzle (m204)
  const int nwg = gridDim.x;
  const int nbx = Ntot >> 8;
  const int q = nwg >> 3, r = nwg & 7;
  const int xcd = blockIdx.x & 7, off = blockIdx.x >> 3;
  const int bid = (xcd < r ? xcd * (q + 1) : r * (q + 1) + (xcd - r) * q) + off;
  const int bm0 = (bid / nbx) << 8;
  const int bn0 = (bid % nbx) << 8;

  f32x4 acc[8][4];
  #pragma unroll
  for (int i = 0; i < 8; ++i)
    #pragma unroll
    for (int j = 0; j < 4; ++j)
      #pragma unroll
      for (int e = 0; e < 4; ++e) acc[i][j][e] = 0.f;

  const int NT = K >> 6;

  // prologue: tile0 fully (A0,B0,B1,A1), then tile1 (B0,A0,B1) -> 14 loads
  stage_half(A,  bm0, K, 0, 0, As[0][0], tid);
  stage_half(Bt, bn0, K, 0, 0, Bs[0][0], tid);
  stage_half(Bt, bn0, K, 0, 1, Bs[0][1], tid);
  stage_half(A,  bm0, K, 0, 1, As[0][1], tid);
  stage_half(Bt, bn0, K, 1, 0, Bs[1][0], tid);
  stage_half(A,  bm0, K, 1, 0, As[1][0], tid);
  stage_half(Bt, bn0, K, 1, 1, Bs[1][1], tid);
  asm volatile("s_waitcnt vmcnt(6)" ::: "memory");
  __builtin_amdgcn_s_barrier();

  int p = 0;
  bf16x8 af[4], bfr[4];
  for (int t = 0; t < NT; ++t, p ^= 1) {
    // ---- phase 0: B ks0 (4) + A rows0-3 ks0 (4); stage (t+1).A-kh1 ----
    #pragma unroll
    for (int j = 0; j < 4; ++j) bfr[j] = frag_ld(Bs[p][0], wn * 64 + j * 16 + lr, lg);
    #pragma unroll
    for (int i = 0; i < 4; ++i) af[i] = frag_ld(As[p][0], wm * 128 + i * 16 + lr, lg);
    if (t + 1 < NT) stage_half(A, bm0, K, t + 1, 1, As[p ^ 1][1], tid);
    __builtin_amdgcn_s_barrier();
    asm volatile("s_waitcnt lgkmcnt(0)" ::: "memory");
    __builtin_amdgcn_sched_barrier(0);
    __builtin_amdgcn_s_setprio(1);
    #pragma unroll
    for (int i = 0; i < 4; ++i)
      #pragma unroll
      for (int j = 0; j < 4; ++j)
        acc[i][j] = __builtin_amdgcn_mfma_f32_16x16x32_bf16(af[i], bfr[j], acc[i][j], 0, 0, 0);
    __builtin_amdgcn_s_setprio(0);
    __builtin_amdgcn_s_barrier();

    // ---- phase 1: A rows4-7 ks0 (4); stage (t+2).B-kh0 ----
    #pragma unroll
    for (int i = 0; i < 4; ++i) af[i] = frag_ld(As[p][0], wm * 128 + (i + 4) * 16 + lr, lg);
    if (t + 2 < NT) stage_half(Bt, bn0, K, t + 2, 0, Bs[p][0], tid);
    __builtin_amdgcn_s_barrier();
    asm volatile("s_waitcnt lgkmcnt(0)" ::: "memory");
    __builtin_amdgcn_sched_barrier(0);
    __builtin_amdgcn_s_setprio(1);
    #pragma unroll
    for (int i = 0; i < 4; ++i)
      #pragma unroll
      for (int j = 0; j < 4; ++j)
        acc[i + 4][j] = __builtin_amdgcn_mfma_f32_16x16x32_bf16(af[i], bfr[j], acc[i + 4][j], 0, 0, 0);
    __builtin_amdgcn_s_setprio(0);
    __builtin_amdgcn_s_barrier();

    // ---- phase 2: B ks1 (4) + A rows0-3 ks1 (4); stage (t+2).A-kh0 ----
    #pragma unroll
    for (int j = 0; j < 4; ++j) bfr[j] = frag_ld(Bs[p][1], wn * 64 + j * 16 + lr, lg);
    #pragma unroll
    for (int i = 0; i < 4; ++i) af[i] = frag_ld(As[p][1], wm * 128 + i * 16 + lr, lg);
    if (t + 2 < NT) stage_half(A, bm0, K, t + 2, 0, As[p][0], tid);
    __builtin_amdgcn_s_barrier();
    asm volatile("s_waitcnt lgkmcnt(0)" ::: "memory");
    __builtin_amdgcn_sched_barrier(0);
    __builtin_amdgcn_s_setprio(1);
    #pragma unroll
    for (int i = 0; i < 4; ++i)
      #pragma unroll
      for (int j = 0; j < 4; ++j)
        acc[i][j] = __builtin_amdgcn_mfma_f32_16x16x32_bf16(af[i], bfr[j], acc[i][j], 0, 0, 0);
    __builtin_amdgcn_s_setprio(0);
    __builtin_amdgcn_s_barrier();

    // ---- phase 3: A rows4-7 ks1 (4); stage (t+2).B-kh1; vmcnt; barrier ----
    #pragma unroll
    for (int i = 0; i < 4; ++i) af[i] = frag_ld(As[p][1], wm * 128 + (i + 4) * 16 + lr, lg);
    if (t + 2 < NT) stage_half(Bt, bn0, K, t + 2, 1, Bs[p][1], tid);
    __builtin_amdgcn_s_barrier();
    asm volatile("s_waitcnt lgkmcnt(0)" ::: "memory");
    __builtin_amdgcn_sched_barrier(0);
    __builtin_amdgcn_s_setprio(1);
    #pragma unroll
    for (int i = 0; i < 4; ++i)
      #pragma unroll
      for (int j = 0; j < 4; ++j)
        acc[i + 4][j] = __builtin_amdgcn_mfma_f32_16x16x32_bf16(af[i], bfr[j], acc[i + 4][j], 0, 0, 0);
    __builtin_amdgcn_s_setprio(0);
    if (t < NT - 3) asm volatile("s_waitcnt vmcnt(6)" ::: "memory");
    else            asm volatile("s_waitcnt vmcnt(0)" ::: "memory");
    __builtin_amdgcn_s_barrier();
  }

  #pragma unroll
  for (int i = 0; i < 8; ++i)
    #pragma unroll
    for (int j = 0; j < 4; ++j) {
      int m = bm0 + wm * 128 + i * 16 + lg * 4;
      int n = bn0 + wn * 64 + j * 16 + lr;
      #pragma unroll
      for (int e = 0; e < 4; ++e) {
        if (F32OUT) ((float*)Cp)[(size_t)(m + e) * Ntot + n] = acc[i][j][e];
        else ((unsigned short*)Cp)[(size_t)(m + e) * Ntot + n] = f2bf(acc[i][j][e]);
      }
    }
}

// ---------- reorg: RoPE(q,k) -> (B,H,T,D); v -> v_t (B,H,D,T) ----------
__global__ __launch_bounds__(256) void k_reorg(const unsigned short* __restrict__ qkv,
                        const float* __restrict__ fcos, const float* __restrict__ fsin,
                        unsigned short* __restrict__ q_r, unsigned short* __restrict__ k_r,
                        unsigned short* __restrict__ v_t) {
  const int bh = blockIdx.x, b = bh >> 4, h = bh & 15;
  const int t0 = blockIdx.y * 64;
  const int tid = threadIdx.x;
  __shared__ unsigned short vt[64][136];
  #pragma unroll
  for (int p = 0; p < 4; ++p) {
    int idx = p * 256 + tid;
    int tl = idx >> 4, sg = idx & 15;
    int t = t0 + tl, d0 = sg * 8;
    float sgn = (d0 < 64) ? -1.f : 1.f;
    float4 c0v = *(const float4*)(fcos + t * D_ + d0);
    float4 c1v = *(const float4*)(fcos + t * D_ + d0 + 4);
    float4 s0v = *(const float4*)(fsin + t * D_ + d0);
    float4 s1v = *(const float4*)(fsin + t * D_ + d0 + 4);
    float cs[8] = {c0v.x,c0v.y,c0v.z,c0v.w,c1v.x,c1v.y,c1v.z,c1v.w};
    float sn[8] = {s0v.x,s0v.y,s0v.z,s0v.w,s1v.x,s1v.y,s1v.z,s1v.w};
    #pragma unroll
    for (int w = 0; w < 2; ++w) {
      const unsigned short* src = qkv + (size_t)(b*T_ + t) * N1_ + w*C_ + h*D_;
      u16x8 a  = *(const u16x8*)(src + d0);
      u16x8 pr = *(const u16x8*)(src + (d0 ^ 64));
      u16x8 o;
      #pragma unroll
      for (int e = 0; e < 8; ++e)
        o[e] = f2bf(bf2f(a[e]) * cs[e] + sgn * bf2f(pr[e]) * sn[e]);
      unsigned short* dst = (w ? k_r : q_r) + (size_t)((b*H_ + h)*T_ + t) * D_ + d0;
      *(u16x8*)dst = o;
    }
    const unsigned short* vsrc = qkv + (size_t)(b*T_ + t) * N1_ + 2*C_ + h*D_ + d0;
    *(u16x8*)&vt[tl][d0] = *(const u16x8*)vsrc;
  }
  __syncthreads();
  #pragma unroll
  for (int p = 0; p < 4; ++p) {
    int idx = p * 256 + tid;
    int sg = idx & 7, d = idx >> 3;
    u16x8 o;
    #pragma unroll
    for (int e = 0; e < 8; ++e) o[e] = vt[sg*8 + e][d];
    *(u16x8*)(v_t + (size_t)((b*H_ + h)*D_ + d) * T_ + t0 + sg*8) = o;
  }
}

// ---------- sliding-window flash attention ----------
__global__ __launch_bounds__(256) void k_attn(const unsigned short* __restrict__ q_r,
                       const unsigned short* __restrict__ k_r,
                       const unsigned short* __restrict__ v_t,
                       unsigned short* __restrict__ y) {
  const int bh = blockIdx.x, b = bh >> 4, h = bh & 15;
  const int q0 = blockIdx.y * 64;
  const int tid = threadIdx.x, lane = tid & 63, wv = tid >> 6;
  const int lr = lane & 15, lg = lane >> 4;

  __shared__ unsigned short Ks[64][136];
  __shared__ unsigned short Vs[128][72];
  __shared__ unsigned short Ps[4][16][80];

  const size_t bhT = (size_t)(b*H_ + h) * T_;
  const unsigned short* qbase = q_r + (bhT + q0 + wv*16 + lr) * D_;
  bf16x8 qf[4];
  #pragma unroll
  for (int kk = 0; kk < 4; ++kk) qf[kk] = *(const bf16x8*)(qbase + kk*32 + lg*8);

  f32x4 o[8];
  #pragma unroll
  for (int i = 0; i < 8; ++i)
    #pragma unroll
    for (int e = 0; e < 4; ++e) o[i][e] = 0.f;
  float m_run[4], l_sum[4];
  #pragma unroll
  for (int e = 0; e < 4; ++e) { m_run[e] = -1e30f; l_sum[e] = 0.f; }

  const int i_min = q0 + wv*16, i_max = i_min + 15;
  int kt_lo = q0 - (W_ - 1); if (kt_lo < 0) kt_lo = 0; kt_lo &= ~63;
  const float scale = 0.08838834764831845f;

  for (int kt = kt_lo; kt < q0 + 64; kt += 64) {
    #pragma unroll
    for (int p = 0; p < 4; ++p) {
      int idx = p*256 + tid;
      int row = idx >> 4, sg = idx & 15;
      *(u16x8*)&Ks[row][sg*8] = *(const u16x8*)(k_r + (bhT + kt + row) * D_ + sg*8);
    }
    #pragma unroll
    for (int p = 0; p < 4; ++p) {
      int idx = p*256 + tid;
      int d = idx >> 3, sg = idx & 7;
      *(u16x8*)&Vs[d][sg*8] = *(const u16x8*)(v_t + ((size_t)(b*H_+h)*D_ + d) * T_ + kt + sg*8);
    }
    __syncthreads();

    if (kt <= i_max && kt + 63 >= i_min - (W_ - 1)) {
      f32x4 s[4];
      #pragma unroll
      for (int ct = 0; ct < 4; ++ct)
        #pragma unroll
        for (int e = 0; e < 4; ++e) s[ct][e] = 0.f;
      #pragma unroll
      for (int kk = 0; kk < 4; ++kk) {
        #pragma unroll
        for (int ct = 0; ct < 4; ++ct) {
          bf16x8 kf = *(const bf16x8*)((const char*)&Ks[ct*16 + lr][0] + kk*64 + lg*16);
          s[ct] = __builtin_amdgcn_mfma_f32_16x16x32_bf16(qf[kk], kf, s[ct], 0, 0, 0);
        }
      }
      #pragma unroll
      for (int e = 0; e < 4; ++e) {
        int i = i_min + lg*4 + e;
        float sv[4];
        float rm = -1e30f;
        #pragma unroll
        for (int ct = 0; ct < 4; ++ct) {
          int j = kt + ct*16 + lr;
          bool ok = (j <= i) && (j > i - W_);
          sv[ct] = ok ? s[ct][e] * scale : -1e30f;
          rm = fmaxf(rm, sv[ct]);
        }
        #pragma unroll
        for (int msk = 1; msk < 16; msk <<= 1) rm = fmaxf(rm, __shfl_xor(rm, msk));
        float mnew = fmaxf(m_run[e], rm);
        float fac = __expf(m_run[e] - mnew);
        float rs = 0.f;
        #pragma unroll
        for (int ct = 0; ct < 4; ++ct) {
          float pv = (sv[ct] > -1e29f) ? __expf(sv[ct] - mnew) : 0.f;
          rs += pv;
          Ps[wv][lg*4 + e][ct*16 + lr] = f2bf(pv);
        }
        #pragma unroll
        for (int msk = 1; msk < 16; msk <<= 1) rs += __shfl_xor(rs, msk);
        l_sum[e] = l_sum[e] * fac + rs;
        m_run[e] = mnew;
        #pragma unroll
        for (int nt = 0; nt < 8; ++nt) o[nt][e] *= fac;
      }
      asm volatile("s_waitcnt lgkmcnt(0)" ::: "memory");
      #pragma unroll
      for (int kk = 0; kk < 2; ++kk) {
        bf16x8 pf = *(const bf16x8*)((const char*)&Ps[wv][lr][0] + kk*64 + lg*16);
        #pragma unroll
        for (int nt = 0; nt < 8; ++nt) {
          bf16x8 vf = *(const bf16x8*)((const char*)&Vs[nt*16 + lr][0] + kk*64 + lg*16);
          o[nt] = __builtin_amdgcn_mfma_f32_16x16x32_bf16(pf, vf, o[nt], 0, 0, 0);
        }
      }
    }
    __syncthreads();
  }

  #pragma unroll
  for (int nt = 0; nt < 8; ++nt) {
    #pragma unroll
    for (int e = 0; e < 4; ++e) {
      int t = q0 + wv*16 + lg*4 + e;
      int d = nt*16 + lr;
      y[(size_t)(b*T_ + t) * C_ + h*D_ + d] = f2bf(o[nt][e] / l_sum[e]);
    }
  }
}

extern "C" void kernel_launch(void* const* d_in, const int* in_sizes, int n_in,
                              void* d_out, int out_size, void* d_ws, size_t ws_size,
                              hipStream_t stream) {
  const float* x      = (const float*)d_in[0];
  const float* fcos   = (const float*)d_in[1];
  const float* fsin   = (const float*)d_in[2];
  const float* w_attn = (const float*)d_in[3];
  const float* w_proj = (const float*)d_in[4];
  float* out = (float*)d_out;

  char* ws = (char*)d_ws;
  unsigned short* x_bf = (unsigned short*)(ws);
  unsigned short* wa_t = (unsigned short*)(ws + 16777216ull);
  unsigned short* wp_t = (unsigned short*)(ws + 41943040ull);
  unsigned short* qkv  = (unsigned short*)(ws + 50331648ull);
  unsigned short* q_r  = (unsigned short*)(ws + 100663296ull);
  unsigned short* k_r  = (unsigned short*)(ws + 117440512ull);
  unsigned short* v_t  = (unsigned short*)(ws + 134217728ull);
  unsigned short* y_bf = x_bf;

  k_cvt<<<dim3(4096), dim3(256), 0, stream>>>(x, x_bf, M_*C_);
  k_tcvt<<<dim3(192, 64), dim3(256), 0, stream>>>(w_attn, wa_t, C_, N1_);
  k_tcvt<<<dim3(64, 64), dim3(256), 0, stream>>>(w_proj, wp_t, C_, C_);
  k_gemm8<false><<<dim3(384), dim3(512), 0, stream>>>(x_bf, wa_t, qkv, N1_, C_);
  k_reorg<<<dim3(32, 32), dim3(256), 0, stream>>>(qkv, fcos, fsin, q_r, k_r, v_t);
  k_attn<<<dim3(32, 32), dim3(256), 0, stream>>>(q_r, k_r, v_t, y_bf);
  k_gemm8<true><<<dim3(128), dim3(512), 0, stream>>>(y_bf, wp_t, out, C_, C_);
}